// Round 8
// baseline (11590.825 us; speedup 1.0000x reference)
//
#include <hip/hip_runtime.h>
#include <math.h>

#define TT 200
#define NDIM 1024
#define IDIM 128
#define ODIM 128
#define NB 256

// ws float offsets (9,437,184 B + 512 B barrier; R2/R3 proved ws >= 11.5 MB)
#define J4_OFF 0          // f32 J4[kq][n][4]: J4[kq*4096 + n*4 + kk] = J[n][4kq+kk]
#define B4_OFF 1048576    // f32 B4[iq][n][4]: B4[iq*4096 + n*4 + ii] = B[n][4iq+ii]
#define W4_OFF 1179648    // f32 W4[kq][o][4]: W4[kq*512 + o*4 + kk]  = W[o][4kq+kk]
#define SG_OFF 1310720    // f32 Sg[2][256][1024] sigmoid(V), natural layout
#define TH_OFF 1835008    // f32 Th[2][256][1024] tanh(V),  natural layout
#define BAR_OFF 2359296   // u32 cnt[32] @ +0, u32 flg[32] @ +64 (u32 index)

// d_out float offsets
#define VT_STRIDE 205824          // 201*1024 per batch
#define ZT_BASE   52690944        // 256*201*1024
#define OUTS_BASE 105381888

__global__ __launch_bounds__(256) void rsnn_prologue(
    const float* __restrict__ J, const float* __restrict__ Bm,
    const float* __restrict__ W, float* __restrict__ ws,
    float* __restrict__ out) {
  const int blk = blockIdx.x, tid = threadIdx.x;
  if (blk < 1024) {
    // J4 pack: n = blk, kq = tid
    float4 v = *(const float4*)(J + (size_t)blk * NDIM + (tid << 2));
    *(float4*)(ws + J4_OFF + (size_t)tid * 4096 + (blk << 2)) = v;
  } else if (blk < 1152) {
    // W4 pack: o = blk-1024 (0..127), kq = tid
    const int o = blk - 1024;
    float4 v = *(const float4*)(W + (size_t)o * NDIM + (tid << 2));
    *(float4*)(ws + W4_OFF + (size_t)tid * 512 + (o << 2)) = v;
  } else if (blk < 1280) {
    // B4 pack: g over 1024 n x 32 iq
    const int g = (blk - 1152) * 256 + tid;
    const int iq = g & 31, n = g >> 5;
    float4 v = *(const float4*)(Bm + (size_t)n * IDIM + (iq << 2));
    *(float4*)(ws + B4_OFF + (size_t)iq * 4096 + (n << 2)) = v;
  } else {
    // init parity-0 state + t=0 output planes + barrier slots
    const int idx = (blk - 1280) * 256 + tid;   // 0..262143
    ws[SG_OFF + idx] = 0.5f;                    // sigmoid(0)
    ws[TH_OFF + idx] = 0.0f;                    // tanh(0)
    const int b = idx >> 10, n = idx & 1023;
    out[(size_t)b * VT_STRIDE + n] = 0.0f;
    out[ZT_BASE + (size_t)b * VT_STRIDE + n] = 0.0f;
    if (idx < 128) ((unsigned*)(ws + BAR_OFF))[idx] = 0u;
  }
}

// Persistent kernel: 512 blocks (bt=blk>>4: 8-batch tile, nt=blk&15: 64-neuron
// tile) x 256 threads (4 waves, wave w = k-chunk). Per-bt group barrier (16
// contiguous blocks) between steps via device-scope atomics + fences.
// Bit-exact R1 chains: per (b,n) k-chunks {0-287,288-575,576-863,864-1023+input},
// reduce ((p0+p1)+p2)+p3; outs 4x256-k chains, ((0+1)+2)+3; verbatim epilogue.
__global__ __launch_bounds__(256, 2) void rsnn_persist(
    const float* __restrict__ inputs, const float* __restrict__ noise,
    float* __restrict__ ws, float* __restrict__ out) {
  const int tid = threadIdx.x;
  const int l = tid & 63;
  const int w = __builtin_amdgcn_readfirstlane(tid >> 6);  // 0..3
  const int bt = blockIdx.x >> 4, nt = blockIdx.x & 15;
  const int b0 = bt << 3;
  const int n = (nt << 6) + l;

  const float* J4 = ws + J4_OFF;
  const float* B4 = ws + B4_OFF;
  const float* W4 = ws + W4_OFF;
  float* Sg = ws + SG_OFF;
  float* Th = ws + TH_OFF;
  unsigned* cnt = (unsigned*)(ws + BAR_OFF) + bt;
  unsigned* flg = (unsigned*)(ws + BAR_OFF) + 64 + bt;

  __shared__ float S_lds[NDIM * 12];   // [k][12-stride], 16B-aligned b128 rows
  __shared__ float X_lds[IDIM * 12];
  __shared__ float red[4][8][64];
  __shared__ float red2[4][64];

  float vreg[2] = {0.f, 0.f};          // V for (b0+w, n), (b0+w+4, n)

  const int sr = tid & 7;              // staging batch row
  const int scg = tid >> 3;            // staging col group 0..31

  for (int s = 0; s <= TT; ++s) {
    if (s) {
      // ---- per-bt group barrier (16 blocks) ----
      __syncthreads();                 // drain this block's stores (vmcnt 0)
      if (tid == 0) {
        __threadfence();               // agent release: L2 writeback
        unsigned prev = __hip_atomic_fetch_add(cnt, 1u, __ATOMIC_RELAXED,
                                               __HIP_MEMORY_SCOPE_AGENT);
        if (prev == 15u) {
          __hip_atomic_store(cnt, 0u, __ATOMIC_RELAXED, __HIP_MEMORY_SCOPE_AGENT);
          __hip_atomic_store(flg, (unsigned)s, __ATOMIC_RELEASE,
                             __HIP_MEMORY_SCOPE_AGENT);
        } else {
          while (__hip_atomic_load(flg, __ATOMIC_RELAXED,
                                   __HIP_MEMORY_SCOPE_AGENT) < (unsigned)s)
            __builtin_amdgcn_s_sleep(2);
        }
        __threadfence();               // agent acquire: cache invalidate
      }
      __syncthreads();
    }

    if (s < TT) {
      // stage S tile (8 b x 1024 k) and X tile (8 b x 128 i), transposed
      const float* Sb = Sg + (size_t)(s & 1) * (NB * NDIM) + (size_t)(b0 + sr) * NDIM;
#pragma unroll
      for (int p = 0; p < 8; ++p) {
        const int k0 = (scg << 2) + (p << 7);
        float4 v = *(const float4*)(Sb + k0);
        S_lds[(k0 + 0) * 12 + sr] = v.x;
        S_lds[(k0 + 1) * 12 + sr] = v.y;
        S_lds[(k0 + 2) * 12 + sr] = v.z;
        S_lds[(k0 + 3) * 12 + sr] = v.w;
      }
      const int ki = scg << 2;
      float4 xv = *(const float4*)(inputs + ((size_t)(b0 + sr) * TT + s) * IDIM + ki);
      X_lds[(ki + 0) * 12 + sr] = xv.x;
      X_lds[(ki + 1) * 12 + sr] = xv.y;
      X_lds[(ki + 2) * 12 + sr] = xv.z;
      X_lds[(ki + 3) * 12 + sr] = xv.w;
    }
    __syncthreads();

    if (s < TT) {
      float acc[8] = {0.f, 0.f, 0.f, 0.f, 0.f, 0.f, 0.f, 0.f};
      const int kb = w * 288;
      const int ke = (kb + 288 < NDIM) ? (kb + 288) : NDIM;
#pragma unroll 4
      for (int k = kb; k < ke; k += 4) {
        float4 jq = *(const float4*)(J4 + (size_t)(k >> 2) * 4096 + (n << 2));
        const float jvals[4] = {jq.x, jq.y, jq.z, jq.w};
#pragma unroll
        for (int kk = 0; kk < 4; ++kk) {
          float4 sA = *(const float4*)&S_lds[(k + kk) * 12];
          float4 sB = *(const float4*)&S_lds[(k + kk) * 12 + 4];
          const float jv = jvals[kk];
          acc[0] = fmaf(sA.x, jv, acc[0]);
          acc[1] = fmaf(sA.y, jv, acc[1]);
          acc[2] = fmaf(sA.z, jv, acc[2]);
          acc[3] = fmaf(sA.w, jv, acc[3]);
          acc[4] = fmaf(sB.x, jv, acc[4]);
          acc[5] = fmaf(sB.y, jv, acc[5]);
          acc[6] = fmaf(sB.z, jv, acc[6]);
          acc[7] = fmaf(sB.w, jv, acc[7]);
        }
      }
      if (w == 3) {   // input projection appended to wave-3's chain (R1 order)
#pragma unroll 4
        for (int i2 = 0; i2 < IDIM; i2 += 4) {
          float4 bq = *(const float4*)(B4 + (size_t)(i2 >> 2) * 4096 + (n << 2));
          const float bvals[4] = {bq.x, bq.y, bq.z, bq.w};
#pragma unroll
          for (int kk = 0; kk < 4; ++kk) {
            float4 xA = *(const float4*)&X_lds[(i2 + kk) * 12];
            float4 xB = *(const float4*)&X_lds[(i2 + kk) * 12 + 4];
            const float bv = bvals[kk];
            acc[0] = fmaf(xA.x, bv, acc[0]);
            acc[1] = fmaf(xA.y, bv, acc[1]);
            acc[2] = fmaf(xA.z, bv, acc[2]);
            acc[3] = fmaf(xA.w, bv, acc[3]);
            acc[4] = fmaf(xB.x, bv, acc[4]);
            acc[5] = fmaf(xB.y, bv, acc[5]);
            acc[6] = fmaf(xB.z, bv, acc[6]);
            acc[7] = fmaf(xB.w, bv, acc[7]);
          }
        }
      }
#pragma unroll
      for (int i = 0; i < 8; ++i) red[w][i][l] = acc[i];
    }

    if (s >= 1) {   // outs for t = s-1: 8 b x 8 o per block, wave w = k-chunk
      const float* Tb = Th + (size_t)(s & 1) * (NB * NDIM);
      const int oi = l >> 3, oo = l & 7;
      const int o = (nt << 3) + oo;
      const float* trow = Tb + (size_t)(b0 + oi) * NDIM;
      float acco = 0.f;
      const int k0b = w << 8;
#pragma unroll 4
      for (int k = k0b; k < k0b + 256; k += 4) {
        float4 tq = *(const float4*)(trow + k);
        float4 wq = *(const float4*)(W4 + (size_t)(k >> 2) * 512 + (o << 2));
        acco = fmaf(tq.x, wq.x, acco);
        acco = fmaf(tq.y, wq.y, acco);
        acco = fmaf(tq.z, wq.z, acco);
        acco = fmaf(tq.w, wq.w, acco);
      }
      red2[w][l] = acco;
    }
    __syncthreads();

    if (s < TT) {
      const int p = (s + 1) & 1;
      float* Sgn = Sg + (size_t)p * (NB * NDIM);
      float* Thn = Th + (size_t)p * (NB * NDIM);
#pragma unroll
      for (int e = 0; e < 2; ++e) {
        const int idx = (e << 8) + tid;       // 0..511 over 8b x 64n
        const int i = idx >> 6, nc = idx & 63;
        float sum = ((red[0][i][nc] + red[1][i][nc]) + red[2][i][nc]) + red[3][i][nc];
        const int b = b0 + i;
        const int n2 = (nt << 6) + nc;
        float vold = vreg[e];
        float vnew = 0.9f * vold + 0.1f * sum;
        vreg[e] = vnew;
        out[(size_t)b * VT_STRIDE + (size_t)(s + 1) * NDIM + n2] = vnew;
        float sg = 1.0f / (1.0f + expf(-vnew));
        Sgn[(size_t)b * NDIM + n2] = sg;
        Thn[(size_t)b * NDIM + n2] = tanhf(vnew);
        float zarg = (0.1f * (vnew - 0.4f)) / 0.4f;
        float zs = 1.0f / (1.0f + expf(-zarg));
        float u = noise[((size_t)b * TT + s) * NDIM + n2];
        out[ZT_BASE + (size_t)b * VT_STRIDE + (size_t)(s + 1) * NDIM + n2] =
            (zs > u) ? 1.0f : 0.0f;
      }
    }

    if (s >= 1 && tid < 64) {
      const int oi = l >> 3, oo = l & 7;
      float sum = ((red2[0][l] + red2[1][l]) + red2[2][l]) + red2[3][l];
      out[OUTS_BASE + ((size_t)(b0 + oi) * TT + (s - 1)) * ODIM + (nt << 3) + oo] = sum;
    }
  }
}

extern "C" void kernel_launch(void* const* d_in, const int* in_sizes, int n_in,
                              void* d_out, int out_size, void* d_ws, size_t ws_size,
                              hipStream_t stream) {
  const float* inputs = (const float*)d_in[0];  // (256,200,128)
  const float* noise  = (const float*)d_in[1];  // (256,200,1024)
  const float* J      = (const float*)d_in[2];  // (1024,1024)
  const float* Bm     = (const float*)d_in[3];  // (1024,128)
  const float* W      = (const float*)d_in[4];  // (128,1024)
  float* out = (float*)d_out;
  float* ws  = (float*)d_ws;

  rsnn_prologue<<<2304, 256, 0, stream>>>(J, Bm, W, ws, out);
  rsnn_persist<<<512, 256, 0, stream>>>(inputs, noise, ws, out);
}